// Round 16
// baseline (315.960 us; speedup 1.0000x reference)
//
#include <hip/hip_runtime.h>
#include <math.h>

#define SK 7680          // 256 segments * 30 samples
#define NPTS 524288

// ---- workspace float offsets ----
#define WS_GQ_PART  0         // 32 partials x (96 sum + 96 sumsq)
#define WS_GK_PART  6144
#define WS_GQ_SCALE 12288
#define WS_GQ_SHIFT 12384
#define WS_GK_SCALE 12480
#define WS_GK_SHIFT 12576
#define WS_SEGX2    21888     // 256*96 raw view2 segment sums
#define WS_SEGG2    46464     // 256*96 head(view2) segment sums
#define WS_ANCHOR1  71040
#define WS_ANCHOR2  95616
#define WS_SAMPT    120192    // [7680][96] raw l2normed samples (row-major)
#define WS_SAMP2T   857472    // [7680][96] head l2normed samples (row-major)
#define WS_SROW     1594752   // [256][7680] sim2 matrix
#define WS_XB       3560832   // v2 as bf16 [524288][96] (chunk-permuted), 100 MB
#define WS_ZERO_CNT 71040     // zero partials + seg sums

typedef __attribute__((ext_vector_type(8))) short bf16x8;
typedef __attribute__((ext_vector_type(4))) float f32x4;

#define AS1 __attribute__((address_space(1)))
#define AS3 __attribute__((address_space(3)))

// async global->LDS, 16B per lane, LDS dst = wave-uniform base + lane*16
__device__ __forceinline__ void gl16(const float* g, char* l){
  __builtin_amdgcn_global_load_lds((const AS1 unsigned*)g, (AS3 unsigned*)l, 16, 0, 0);
}
__device__ __forceinline__ void gl16b(const char* g, char* l){
  __builtin_amdgcn_global_load_lds((const AS1 unsigned*)g, (AS3 unsigned*)l, 16, 0, 0);
}

// v_cvt_pk_bf16_f32 packing
__device__ __forceinline__ bf16x8 pack8(float4 a, float4 b){
  union { unsigned u[4]; bf16x8 v; } r;
  asm("v_cvt_pk_bf16_f32 %0, %1, %2" : "=v"(r.u[0]) : "v"(a.x), "v"(a.y));
  asm("v_cvt_pk_bf16_f32 %0, %1, %2" : "=v"(r.u[1]) : "v"(a.z), "v"(a.w));
  asm("v_cvt_pk_bf16_f32 %0, %1, %2" : "=v"(r.u[2]) : "v"(b.x), "v"(b.y));
  asm("v_cvt_pk_bf16_f32 %0, %1, %2" : "=v"(r.u[3]) : "v"(b.z), "v"(b.w));
  return r.v;
}
__device__ __forceinline__ bf16x8 pack8v(f32x4 a, f32x4 b){
  union { unsigned u[4]; bf16x8 v; } r;
  asm("v_cvt_pk_bf16_f32 %0, %1, %2" : "=v"(r.u[0]) : "v"(a[0]), "v"(a[1]));
  asm("v_cvt_pk_bf16_f32 %0, %1, %2" : "=v"(r.u[1]) : "v"(a[2]), "v"(a[3]));
  asm("v_cvt_pk_bf16_f32 %0, %1, %2" : "=v"(r.u[2]) : "v"(b[0]), "v"(b[1]));
  asm("v_cvt_pk_bf16_f32 %0, %1, %2" : "=v"(r.u[3]) : "v"(b[2]), "v"(b[3]));
  return r.v;
}
__device__ __forceinline__ float4 ld4(const float* p){
  return *reinterpret_cast<const float4*>(p);
}
__device__ __forceinline__ uint4 asu4(bf16x8 a){
  union { bf16x8 v; uint4 u; } c; c.v = a; return c.u;
}

// per-wave W fragments in registers: wf[i][kt], i = local ot index (global ot = oh*3+i)
__device__ __forceinline__ void build_wf(const float* __restrict__ W, bf16x8 wf[3][3],
                                         int oh, int lr, int g){
  #pragma unroll
  for (int i=0;i<3;i++){
    const float* wr = W + (unsigned)((oh*3+i)*16+lr)*96 + g*8;
    #pragma unroll
    for (int kt=0;kt<3;kt++)
      wf[i][kt] = pack8(ld4(wr + kt*32), ld4(wr + kt*32 + 4));
  }
}

// non-storing waves: steady 9 (3 tiles ahead), tail 6/3/0
#define VMC_WAIT(it)                                                   \
  if ((it) <= 4)      { asm volatile("s_waitcnt vmcnt(9)" ::: "memory"); } \
  else if ((it) == 5) { asm volatile("s_waitcnt vmcnt(6)" ::: "memory"); } \
  else if ((it) == 6) { asm volatile("s_waitcnt vmcnt(3)" ::: "memory"); } \
  else                { asm volatile("s_waitcnt vmcnt(0)" ::: "memory"); }
// storing waves: FIFO-position upper bounds with 3 stores interleaved per iter
#define VMC_WAIT_S(it)                                                 \
  if ((it)==0)      { asm volatile("s_waitcnt vmcnt(9)"  ::: "memory"); } \
  else if ((it)==1) { asm volatile("s_waitcnt vmcnt(12)" ::: "memory"); } \
  else if ((it)==2) { asm volatile("s_waitcnt vmcnt(15)" ::: "memory"); } \
  else if ((it)==3) { asm volatile("s_waitcnt vmcnt(18)" ::: "memory"); } \
  else if ((it)==4) { asm volatile("s_waitcnt vmcnt(21)" ::: "memory"); } \
  else if ((it)==5) { asm volatile("s_waitcnt vmcnt(18)" ::: "memory"); } \
  else if ((it)==6) { asm volatile("s_waitcnt vmcnt(15)" ::: "memory"); } \
  else              { asm volatile("s_waitcnt vmcnt(12)" ::: "memory"); }

// ---- stats over BOTH views: per-channel sum/sumsq of y = x @ W^T.
// isv2 blocks additionally: raw colsums (SEGX2) + bf16 copy of v2 -> xb.
__global__ __launch_bounds__(256) void stats_both(
    const float* __restrict__ V1, const float* __restrict__ V2,
    const float* __restrict__ Wk, const float* __restrict__ Wq,
    float* __restrict__ gpartK, float* __restrict__ gpartQ,
    float* __restrict__ gseg, char* __restrict__ xb)
{
  __shared__ __align__(16) float xtile[4][3072];   // 4 x 12288 B
  __shared__ float red[96];
  __shared__ float red2[96];
  __shared__ float rsg[96];
  const int tid = threadIdx.x;
  const int l = tid & 63, w = tid >> 6;
  const int g = l >> 4, lr = l & 15;
  const int rg = w & 1, oh = w >> 1;
  const int R = rg*16 + lr;

  const int r_ = blockIdx.x & 15;
  const int g_ = blockIdx.x >> 4;        // [0,256)
  const bool isv2 = (r_ >= 8);
  const int  sub  = (r_ & 7) * 256 + g_; // [0,2048) per view
  const float* X = isv2 ? V2 : V1;
  const float* W = isv2 ? Wq : Wk;
  const bool store_wave = isv2 && (oh == 0);

  bf16x8 wf[3][3];
  build_wf(W, wf, oh, lr, g);
  if (tid < 96){ red[tid]=0.f; red2[tid]=0.f; rsg[tid]=0.f; }

  int so[3];
  #pragma unroll
  for (int i=0;i<3;i++){
    int s = i*256 + tid;
    int r = s/24, cp = s%24;
    int c = (cp & ~7) | ((cp & 7) ^ (r & 7));
    so[i] = r*96 + c*4;
  }
  const float* base = X + (long)sub*24576;
  char* lbase_c = (char*)&xtile[0][0] + w*1024;

  unsigned lb = (unsigned)(uintptr_t)&xtile[0][0];
  const unsigned a0base = lb + R*384 + (unsigned)((( 2*g   ) ^ (R&7))*16);
  const unsigned a1base = lb + R*384 + (unsigned)((((2*g)|1) ^ (R&7))*16);

  // bf16 store: row = sub*256 + it*32 + R; position q = g ^ perm(R)
  const int qchunk = (g ^ ((R>>1)&3)) ^ (R&3);
  char* xb_ptr = xb + (size_t)(sub*256 + R)*192 + (size_t)qchunk*16;

#define STAGE(t) {                                        \
    const float* tb = base + (t)*3072;                    \
    char* ld = lbase_c + ((t)&3)*12288;                   \
    gl16(tb + so[0], ld);                                 \
    gl16(tb + so[1], ld + 4096);                          \
    gl16(tb + so[2], ld + 8192); }

  STAGE(0) STAGE(1) STAGE(2) STAGE(3)

  float sY[3]={0.f,0.f,0.f}, sY2[3]={0.f,0.f,0.f};
  f32x4 csA0={0,0,0,0}, csA1={0,0,0,0}, csA2={0,0,0,0};
  f32x4 csB0={0,0,0,0}, csB1={0,0,0,0}, csB2={0,0,0,0};

  #pragma unroll 1
  for (int it=0; it<8; ++it){
    if (store_wave){ VMC_WAIT_S(it) } else { VMC_WAIT(it) }
    __builtin_amdgcn_s_barrier();
    const unsigned boff = (unsigned)(it&3)*12288u;
    unsigned addrA = a0base + boff, addrB = a1base + boff;
    f32x4 xA0,xA1,xA2,xB0,xB1,xB2;
    asm volatile(
      "ds_read_b128 %0, %6\n\t"
      "ds_read_b128 %1, %6 offset:128\n\t"
      "ds_read_b128 %2, %6 offset:256\n\t"
      "ds_read_b128 %3, %7\n\t"
      "ds_read_b128 %4, %7 offset:128\n\t"
      "ds_read_b128 %5, %7 offset:256\n\t"
      "s_waitcnt lgkmcnt(0)"
      : "=&v"(xA0),"=&v"(xA1),"=&v"(xA2),"=&v"(xB0),"=&v"(xB1),"=&v"(xB2)
      : "v"(addrA), "v"(addrB) : "memory");
    __builtin_amdgcn_sched_barrier(0);
    __builtin_amdgcn_s_barrier();
    bf16x8 a0 = pack8v(xA0,xB0), a1 = pack8v(xA1,xB1), a2 = pack8v(xA2,xB2);
    if (it<4) STAGE(it+4)
    if (store_wave){
      csA0[0]+=xA0[0]; csA0[1]+=xA0[1]; csA0[2]+=xA0[2]; csA0[3]+=xA0[3];
      csA1[0]+=xA1[0]; csA1[1]+=xA1[1]; csA1[2]+=xA1[2]; csA1[3]+=xA1[3];
      csA2[0]+=xA2[0]; csA2[1]+=xA2[1]; csA2[2]+=xA2[2]; csA2[3]+=xA2[3];
      csB0[0]+=xB0[0]; csB0[1]+=xB0[1]; csB0[2]+=xB0[2]; csB0[3]+=xB0[3];
      csB1[0]+=xB1[0]; csB1[1]+=xB1[1]; csB1[2]+=xB1[2]; csB1[3]+=xB1[3];
      csB2[0]+=xB2[0]; csB2[1]+=xB2[1]; csB2[2]+=xB2[2]; csB2[3]+=xB2[3];
      uint4* xp = reinterpret_cast<uint4*>(xb_ptr + it*6144);
      xp[0] = asu4(a0);   // chunk g     (content: bf16 k [8g..8g+8))
      xp[4] = asu4(a1);   // chunk 4+g
      xp[8] = asu4(a2);   // chunk 8+g
    }
    #pragma unroll
    for (int i=0;i<3;i++){
      f32x4 acc = {0.f,0.f,0.f,0.f};
      acc = __builtin_amdgcn_mfma_f32_16x16x32_bf16(a0, wf[i][0], acc, 0,0,0);
      acc = __builtin_amdgcn_mfma_f32_16x16x32_bf16(a1, wf[i][1], acc, 0,0,0);
      acc = __builtin_amdgcn_mfma_f32_16x16x32_bf16(a2, wf[i][2], acc, 0,0,0);
      sY[i]  += acc[0]+acc[1]+acc[2]+acc[3];
      sY2[i]  = fmaf(acc[0],acc[0],fmaf(acc[1],acc[1],
                fmaf(acc[2],acc[2],fmaf(acc[3],acc[3],sY2[i]))));
    }
  }
#undef STAGE

  __syncthreads();
  #pragma unroll
  for (int i=0;i<3;i++){
    float s = sY[i], s2 = sY2[i];
    s  += __shfl_xor(s,16);  s  += __shfl_xor(s,32);
    s2 += __shfl_xor(s2,16); s2 += __shfl_xor(s2,32);
    if (g==0){
      atomicAdd(&red[(oh*3+i)*16+lr],  s);
      atomicAdd(&red2[(oh*3+i)*16+lr], s2);
    }
  }
  if (store_wave){
    // content chunks: A-set = 2g (+8,+16), B-set = 2g+1 (+8,+16)
    const int cA = 2*g, cB = 2*g+1;
    #pragma unroll
    for (int k=0;k<4;k++){
      atomicAdd(&rsg[cA*4+k],      csA0[k]);
      atomicAdd(&rsg[(cA+8)*4+k],  csA1[k]);
      atomicAdd(&rsg[(cA+16)*4+k], csA2[k]);
      atomicAdd(&rsg[cB*4+k],      csB0[k]);
      atomicAdd(&rsg[(cB+8)*4+k],  csB1[k]);
      atomicAdd(&rsg[(cB+16)*4+k], csB2[k]);
    }
  }
  __syncthreads();
  if (tid<96){
    float* dst = (isv2 ? gpartQ : gpartK) + (sub & 31)*192;
    atomicAdd(dst+tid,    red[tid]);
    atomicAdd(dst+96+tid, red2[tid]);
    if (isv2) atomicAdd(gseg + (sub>>3)*96 + tid, rsg[tid]);
  }
}

// ---- apply pass: reads xb (v2 bf16, chunk-permuted), relu(BN(y)) per-segment sums.
// 2048 blocks x 4 tiles of 64 rows (12 KB), depth-2 pipeline.
__global__ __launch_bounds__(256) void head_apply_bf16(
    const char* __restrict__ xb, const float* __restrict__ W,
    const float* __restrict__ scale, const float* __restrict__ shift,
    float* __restrict__ gsegBN)
{
  __shared__ __align__(16) char xt[2][12288];
  __shared__ float red[96];
  const int tid = threadIdx.x;
  const int l = tid & 63, w = tid >> 6;
  const int g = l >> 4, lr = l & 15;
  const int rg = w & 1, oh = w >> 1;
  const int Rr = rg*16 + lr;               // LDS row (set 0); set 1 adds 32

  bf16x8 wf[3][3];
  build_wf(W, wf, oh, lr, g);
  if (tid < 96) red[tid]=0.f;

  float sc[3], sh[3];
  #pragma unroll
  for (int i=0;i<3;i++){
    sc[i]=scale[(oh*3+i)*16+lr]; sh[i]=shift[(oh*3+i)*16+lr];
  }

  const char* base = xb + (size_t)blockIdx.x*4*12288;
  char* lbase = &xt[0][0] + w*1024;        // wave-uniform LDS base (+lane*16 implicit)
  unsigned lb = (unsigned)(uintptr_t)&xt[0][0];
  // read position q0 = g ^ perm(Rr) retrieves content chunk g (identity mapping)
  const unsigned q0 = (unsigned)((g ^ ((Rr>>1)&3)) ^ (Rr&3));
  const unsigned afb0 = lb + (unsigned)(Rr*192) + q0*16u;
  const unsigned afb1 = afb0 + 32u*192u;   // perm(R+32)==perm(R)

#define STAGE(t) {                                        \
    const char* tb = base + (t)*12288;                    \
    char* ld = lbase + ((t)&1)*12288;                     \
    gl16b(tb + tid*16,        ld);                        \
    gl16b(tb + 4096 + tid*16, ld + 4096);                 \
    gl16b(tb + 8192 + tid*16, ld + 8192); }

  STAGE(0) STAGE(1)

  float zs[3]={0.f,0.f,0.f};

  #pragma unroll 1
  for (int t=0; t<4; ++t){
    if (t<3){ asm volatile("s_waitcnt vmcnt(3)" ::: "memory"); }
    else    { asm volatile("s_waitcnt vmcnt(0)" ::: "memory"); }
    __builtin_amdgcn_s_barrier();
    const unsigned boff = (unsigned)(t&1)*12288u;
    unsigned aS0 = afb0 + boff, aS1 = afb1 + boff;
    bf16x8 f00,f01,f02,f10,f11,f12;
    asm volatile(
      "ds_read_b128 %0, %6\n\t"
      "ds_read_b128 %1, %6 offset:64\n\t"
      "ds_read_b128 %2, %6 offset:128\n\t"
      "ds_read_b128 %3, %7\n\t"
      "ds_read_b128 %4, %7 offset:64\n\t"
      "ds_read_b128 %5, %7 offset:128\n\t"
      "s_waitcnt lgkmcnt(0)"
      : "=&v"(f00),"=&v"(f01),"=&v"(f02),"=&v"(f10),"=&v"(f11),"=&v"(f12)
      : "v"(aS0), "v"(aS1) : "memory");
    __builtin_amdgcn_sched_barrier(0);
    __builtin_amdgcn_s_barrier();
    if (t<2) STAGE(t+2)
    #pragma unroll
    for (int i=0;i<3;i++){
      f32x4 acc = {0.f,0.f,0.f,0.f};
      acc = __builtin_amdgcn_mfma_f32_16x16x32_bf16(f00, wf[i][0], acc, 0,0,0);
      acc = __builtin_amdgcn_mfma_f32_16x16x32_bf16(f01, wf[i][1], acc, 0,0,0);
      acc = __builtin_amdgcn_mfma_f32_16x16x32_bf16(f02, wf[i][2], acc, 0,0,0);
      zs[i] += fmaxf(fmaf(acc[0],sc[i],sh[i]),0.f)
             + fmaxf(fmaf(acc[1],sc[i],sh[i]),0.f)
             + fmaxf(fmaf(acc[2],sc[i],sh[i]),0.f)
             + fmaxf(fmaf(acc[3],sc[i],sh[i]),0.f);
    }
    #pragma unroll
    for (int i=0;i<3;i++){
      f32x4 acc = {0.f,0.f,0.f,0.f};
      acc = __builtin_amdgcn_mfma_f32_16x16x32_bf16(f10, wf[i][0], acc, 0,0,0);
      acc = __builtin_amdgcn_mfma_f32_16x16x32_bf16(f11, wf[i][1], acc, 0,0,0);
      acc = __builtin_amdgcn_mfma_f32_16x16x32_bf16(f12, wf[i][2], acc, 0,0,0);
      zs[i] += fmaxf(fmaf(acc[0],sc[i],sh[i]),0.f)
             + fmaxf(fmaf(acc[1],sc[i],sh[i]),0.f)
             + fmaxf(fmaf(acc[2],sc[i],sh[i]),0.f)
             + fmaxf(fmaf(acc[3],sc[i],sh[i]),0.f);
    }
  }
#undef STAGE

  __syncthreads();
  #pragma unroll
  for (int i=0;i<3;i++){
    float s = zs[i];
    s += __shfl_xor(s,16); s += __shfl_xor(s,32);
    if (g==0) atomicAdd(&red[(oh*3+i)*16+lr], s);
  }
  __syncthreads();
  if (tid<96) atomicAdd(gsegBN + (blockIdx.x>>3)*96 + tid, red[tid]);
}

// BN scale/shift from 32 partial sums (training-mode batch stats, biased var)
__global__ void bn_params_kernel(const float* __restrict__ gq_gamma, const float* __restrict__ gq_beta,
                                 const float* __restrict__ gk_gamma, const float* __restrict__ gk_beta,
                                 float* __restrict__ ws)
{
  const int t = threadIdx.x;
  const float invN = 1.0f/(float)NPTS;
  if (t < 96){
    float s=0.f, s2=0.f;
    #pragma unroll 4
    for (int p=0;p<32;p++){
      s  += ws[WS_GQ_PART + p*192 + t];
      s2 += ws[WS_GQ_PART + p*192 + 96 + t];
    }
    float mu  = s*invN;
    float var = s2*invN - mu*mu;
    float sc  = gq_gamma[t]*rsqrtf(var + 1e-5f);
    ws[WS_GQ_SCALE+t] = sc;
    ws[WS_GQ_SHIFT+t] = gq_beta[t] - mu*sc;
  } else if (t < 192){
    int c = t-96;
    float s=0.f, s2=0.f;
    #pragma unroll 4
    for (int p=0;p<32;p++){
      s  += ws[WS_GK_PART + p*192 + c];
      s2 += ws[WS_GK_PART + p*192 + 96 + c];
    }
    float mu  = s*invN;
    float var = s2*invN - mu*mu;
    float sc  = gk_gamma[c]*rsqrtf(var + 1e-5f);
    ws[WS_GK_SCALE+c] = sc;
    ws[WS_GK_SHIFT+c] = gk_beta[c] - mu*sc;
  }
}

// both anchors in one launch
__global__ __launch_bounds__(128) void anchor2x_kernel(
    const float* __restrict__ seg1, float* __restrict__ dst1,
    const float* __restrict__ seg2, float* __restrict__ dst2)
{
  __shared__ float red[128];
  const int t = threadIdx.x, s = blockIdx.x & 255;
  const float* segsum = (blockIdx.x < 256) ? seg1 : seg2;
  float* dst          = (blockIdx.x < 256) ? dst1 : dst2;
  float m = 0.f;
  if (t<96) m = segsum[s*96+t] * (1.0f/2048.0f);
  red[t] = m*m;
  __syncthreads();
  for (int off=64; off>0; off>>=1){
    if (t<off) red[t]+=red[t+off];
    __syncthreads();
  }
  float inv = 1.0f/(sqrtf(red[0]) + 1e-7f);
  if (t<96) dst[s*96+t] = m*inv;
}

// ---- fp32 96x96 tile GEMM helpers (used only by samples_kernel) ----
__device__ __forceinline__ void fma_row(float4& acc, const float4 x,
    const float4 w0, const float4 w1, const float4 w2, const float4 w3){
  acc.x = fmaf(x.x,w0.x, fmaf(x.y,w1.x, fmaf(x.z,w2.x, fmaf(x.w,w3.x, acc.x))));
  acc.y = fmaf(x.x,w0.y, fmaf(x.y,w1.y, fmaf(x.z,w2.y, fmaf(x.w,w3.y, acc.y))));
  acc.z = fmaf(x.x,w0.z, fmaf(x.y,w1.z, fmaf(x.z,w2.z, fmaf(x.w,w3.z, acc.z))));
  acc.w = fmaf(x.x,w0.w, fmaf(x.y,w1.w, fmaf(x.z,w2.w, fmaf(x.w,w3.w, acc.w))));
}
__device__ __forceinline__ void load_W(const float* __restrict__ W, float* Ws, int tid){
  #pragma unroll
  for (int i=0;i<12;i++){
    int f = i*768 + tid*4;
    int oc = f/96, k = f%96;
    float4 w4 = *reinterpret_cast<const float4*>(W + f);
    Ws[(k+0)*100+oc]=w4.x; Ws[(k+1)*100+oc]=w4.y;
    Ws[(k+2)*100+oc]=w4.z; Ws[(k+3)*100+oc]=w4.w;
  }
}
__device__ __forceinline__ void gemm_tile(const float* Xs, const float* Ws,
    int ocg, int rowg, int r0, float4 acc[4]){
  const float4* Xs4 = reinterpret_cast<const float4*>(Xs);
  const float4* Ws4 = reinterpret_cast<const float4*>(Ws);
  acc[0]=acc[1]=acc[2]=acc[3]=make_float4(0.f,0.f,0.f,0.f);
  #pragma unroll 4
  for (int k4=0;k4<24;k4++){
    float4 w0 = Ws4[(k4*4+0)*25 + ocg];
    float4 w1 = Ws4[(k4*4+1)*25 + ocg];
    float4 w2 = Ws4[(k4*4+2)*25 + ocg];
    float4 w3 = Ws4[(k4*4+3)*25 + ocg];
    #pragma unroll
    for (int jj=0;jj<4;jj++){
      float4 xv = Xs4[(r0+jj)*25 + (k4 ^ rowg)];
      fma_row(acc[jj], xv, w0, w1, w2, w3);
    }
  }
}

// gather 32 sampled view1 rows -> raw l2norm + gk-head l2norm, stored ROW-MAJOR [7680][96]
__global__ __launch_bounds__(192) void samples_kernel(
    const float* __restrict__ V1, const float* __restrict__ W,
    const float* __restrict__ scale, const float* __restrict__ shift,
    const int* __restrict__ idxs,
    float* __restrict__ sampT, float* __restrict__ samp2T)
{
  __shared__ __align__(16) float Ws[9600];
  __shared__ __align__(16) float Xs[3200];
  __shared__ __align__(16) float Gs[3200];
  __shared__ float invr[32], invh[32];
  const int tid = threadIdx.x;
  const int ocg = tid % 24, rowg = tid / 24;
  const int oc0 = ocg*4,  r0  = rowg*4;
  load_W(W, Ws, tid);
  const int base = blockIdx.x * 32;
  #pragma unroll
  for (int i=0;i<4;i++){
    int f = i*768 + tid*4;
    int row = f/96, col = f%96;
    int g = idxs[base+row];
    float4 v = *reinterpret_cast<const float4*>(V1 + g*96 + col);
    *reinterpret_cast<float4*>(Xs + row*100 + (col ^ ((row>>2)<<2))) = v;
  }
  __syncthreads();
  if (tid<32){
    float s=0.f;
    #pragma unroll
    for (int k=0;k<96;k++){ float v=Xs[tid*100+(k^((tid>>2)<<2))]; s=fmaf(v,v,s); }
    invr[tid]=1.0f/(sqrtf(s)+1e-7f);
  }
  __syncthreads();
  {
    int rr=tid&31, kg=tid>>5;
    float inv=invr[rr];
    #pragma unroll
    for (int kk=0;kk<16;kk++){
      int k=kg*16+kk;
      sampT[(long)(base+rr)*96 + k] = Xs[rr*100 + (k ^ ((rr>>2)<<2))]*inv;
    }
  }
  float4 acc[4];
  gemm_tile(Xs, Ws, ocg, rowg, r0, acc);
  float4 sc = make_float4(scale[oc0],scale[oc0+1],scale[oc0+2],scale[oc0+3]);
  float4 sh = make_float4(shift[oc0],shift[oc0+1],shift[oc0+2],shift[oc0+3]);
  #pragma unroll
  for (int jj=0;jj<4;jj++){
    int rr=r0+jj;
    float4 g;
    g.x=fmaxf(fmaf(acc[jj].x,sc.x,sh.x),0.f);
    g.y=fmaxf(fmaf(acc[jj].y,sc.y,sh.y),0.f);
    g.z=fmaxf(fmaf(acc[jj].z,sc.z,sh.z),0.f);
    g.w=fmaxf(fmaf(acc[jj].w,sc.w,sh.w),0.f);
    *reinterpret_cast<float4*>(Gs + rr*100 + (oc0 ^ ((rr>>2)<<2))) = g;
  }
  __syncthreads();
  if (tid<32){
    float s=0.f;
    #pragma unroll
    for (int k=0;k<96;k++){ float v=Gs[tid*100+(k^((tid>>2)<<2))]; s=fmaf(v,v,s); }
    invh[tid]=1.0f/(sqrtf(s)+1e-7f);
  }
  __syncthreads();
  {
    int rr=tid&31, kg=tid>>5;
    float inv=invh[rr];
    #pragma unroll
    for (int kk=0;kk<16;kk++){
      int k=kg*16+kk;
      samp2T[(long)(base+rr)*96 + k] = Gs[rr*100 + (k ^ ((rr>>2)<<2))]*inv;
    }
  }
}

// ---- sim2 = anchor2 @ samples2^T via MFMA: grid (30 col-tiles, 16 row-tiles) ----
__global__ __launch_bounds__(256) void sim2_mfma(
    const float* __restrict__ anchor2, const float* __restrict__ samp2,  // samp2 [7680][96]
    float* __restrict__ srowG)
{
  const int tid = threadIdx.x;
  const int l = tid & 63, w = tid >> 6;
  const int g = l >> 4, lr = l & 15;
  const int rowbase = blockIdx.y * 16;
  const int colbase = blockIdx.x * 256 + w * 64;

  bf16x8 af[3];
  const float* ar = anchor2 + (rowbase + lr)*96 + g*8;
  #pragma unroll
  for (int kt=0; kt<3; ++kt)
    af[kt] = pack8(ld4(ar + kt*32), ld4(ar + kt*32 + 4));

  #pragma unroll
  for (int sub=0; sub<4; ++sub){
    const float* br = samp2 + (long)(colbase + sub*16 + lr)*96 + g*8;
    float4 b00 = ld4(br);    float4 b01 = ld4(br+4);
    float4 b10 = ld4(br+32); float4 b11 = ld4(br+36);
    float4 b20 = ld4(br+64); float4 b21 = ld4(br+68);
    f32x4 acc = {0.f,0.f,0.f,0.f};
    acc = __builtin_amdgcn_mfma_f32_16x16x32_bf16(af[0], pack8(b00,b01), acc, 0,0,0);
    acc = __builtin_amdgcn_mfma_f32_16x16x32_bf16(af[1], pack8(b10,b11), acc, 0,0,0);
    acc = __builtin_amdgcn_mfma_f32_16x16x32_bf16(af[2], pack8(b20,b21), acc, 0,0,0);
    const int col  = colbase + sub*16 + lr;
    const int row0 = rowbase + g*4;
    #pragma unroll
    for (int i=0;i<4;i++)
      srowG[(long)(row0+i)*SK + col] = acc[i];
  }
}

// ---- fused Lcon1 + Lcon2: blocks 0..255 lcon2, 256..511 lcon1 (wave 0 only)
__global__ __launch_bounds__(256) void lcon12_kernel(
    const float* __restrict__ anchor1, const float* __restrict__ sampT,
    const float* __restrict__ srowG, const int* __restrict__ bg,
    float* __restrict__ out)
{
  const int tid = threadIdx.x;
  if (blockIdx.x >= 256){
    __shared__ float a[96];
    const int r = blockIdx.x - 256;
    if (tid < 64){
      for (int i=tid;i<96;i+=64) a[i]=anchor1[r*96+i];
      int c = 0;
      if (tid<30) c = r*30+tid;
      else if (tid<60){
        int j = tid-30;
        int p = (int)((double)j * 7649.0 / 29.0);   // linspace(0, M-1, 30).astype(int32)
        c = (p < r*30) ? p : p+30;                  // skip own block
      }
      float s=0.f;
      if (tid<60){
        const float* sr = sampT + (long)c*96;
        #pragma unroll
        for (int k4=0;k4<24;k4++){
          float4 v = *reinterpret_cast<const float4*>(sr + k4*4);
          s = fmaf(a[k4*4+0],v.x, fmaf(a[k4*4+1],v.y,
              fmaf(a[k4*4+2],v.z, fmaf(a[k4*4+3],v.w, s))));
        }
      }
      float logit = 2.0f*s;                          // /T, T=0.5
      float se = (tid<60) ? expf(logit) : 0.f;
      float sp = (tid<30) ? logit : 0.f;
      #pragma unroll
      for (int off=32; off; off>>=1){ se += __shfl_xor(se,off); sp += __shfl_xor(sp,off); }
      if (tid==0){
        float row = sp*(1.0f/30.0f) - logf(se);
        atomicAdd(out, -row*(1.0f/256.0f));
      }
    }
    return;
  }
  __shared__ float wvv[4];
  __shared__ int   wcc[4];
  __shared__ int   winc_s;
  __shared__ int   sel[30];
  const int r = blockIdx.x;
  const int lane = tid & 63, wid = tid >> 6;
  const float* __restrict__ rowp = srowG + (long)r*SK;
  float val[30];
  #pragma unroll
  for (int j=0;j<30;j++) val[j] = rowp[(j<<8) + tid];
  unsigned mask=0; float possum=0.f;
  for (int it=0; it<30; ++it){
    float bv = -3.0e38f; int bc = 1<<30;
    #pragma unroll
    for (int j=0;j<30;j++){
      if (!((mask>>j)&1u)){
        float v = val[j]; int c = tid + (j<<8);
        if (v > bv || (v == bv && c < bc)){ bv=v; bc=c; }
      }
    }
    #pragma unroll
    for (int off=32; off; off>>=1){
      float ov = __shfl_xor(bv, off); int ocx = __shfl_xor(bc, off);
      if (ov > bv || (ov == bv && ocx < bc)){ bv=ov; bc=ocx; }
    }
    if (lane==0){ wvv[wid]=bv; wcc[wid]=bc; }
    __syncthreads();
    if (tid==0){
      float v=wvv[0]; int c=wcc[0];
      #pragma unroll
      for (int w2=1;w2<4;w2++){
        if (wvv[w2]>v || (wvv[w2]==v && wcc[w2]<c)){ v=wvv[w2]; c=wcc[w2]; }
      }
      winc_s=c; sel[it]=c; possum += v;
    }
    __syncthreads();
    int c = winc_s;
    if ((c & 255) == tid) mask |= 1u << (c >> 8);
  }
  const int bgr = bg[r];
  float se=0.f;
  #pragma unroll
  for (int j=0;j<30;j++){
    int c = tid + (j<<8);
    int seg = c/30;
    int bgc = bg[seg];
    bool nf = ((bgr!=0) ? (bgc==0) : (bgc!=0)) && (seg != r);
    if (nf) se += expf(2.0f*val[j]);
  }
  #pragma unroll
  for (int off=32; off; off>>=1) se += __shfl_xor(se, off);
  if (lane==0) wvv[wid]=se;
  __syncthreads();
  float ex=0.f;
  if (tid<30){
    int c = sel[tid]; int seg=c/30; int bgc=bg[seg];
    bool nf = ((bgr!=0) ? (bgc==0) : (bgc!=0)) && (seg != r);
    if (!nf) ex = expf(2.0f*rowp[c]);        // positive not already in denom via neg
  }
  if (wid==0){
    #pragma unroll
    for (int off=32; off; off>>=1) ex += __shfl_xor(ex, off);
  }
  if (tid==0){
    float lse = logf(wvv[0]+wvv[1]+wvv[2]+wvv[3] + ex);
    float row = possum*(2.0f/30.0f) - lse;
    atomicAdd(out, -row*(1.0f/256.0f));
  }
}

extern "C" void kernel_launch(void* const* d_in, const int* in_sizes, int n_in,
                              void* d_out, int out_size, void* d_ws, size_t ws_size,
                              hipStream_t stream) {
  (void)in_sizes; (void)n_in; (void)out_size; (void)ws_size;
  const float* v1       = (const float*)d_in[0];
  const float* v2       = (const float*)d_in[1];
  const float* gq_w     = (const float*)d_in[2];
  const float* gq_gamma = (const float*)d_in[4];
  const float* gq_beta  = (const float*)d_in[5];
  const float* gk_w     = (const float*)d_in[6];
  const float* gk_gamma = (const float*)d_in[8];
  const float* gk_beta  = (const float*)d_in[9];
  const int*   idxs     = (const int*)d_in[12];
  const int*   bg       = (const int*)d_in[13];
  float* ws  = (float*)d_ws;
  float* out = (float*)d_out;
  char*  xb  = (char*)(ws + WS_XB);

  (void)hipMemsetAsync(ws, 0, (size_t)WS_ZERO_CNT*sizeof(float), stream);
  (void)hipMemsetAsync(out, 0, sizeof(float), stream);

  stats_both<<<4096,256,0,stream>>>(v1, v2, gk_w, gq_w,
                                    ws+WS_GK_PART, ws+WS_GQ_PART, ws+WS_SEGX2, xb);
  bn_params_kernel<<<1,192,0,stream>>>(gq_gamma, gq_beta, gk_gamma, gk_beta, ws);
  samples_kernel<<<240,192,0,stream>>>(v1, gk_w, ws+WS_GK_SCALE, ws+WS_GK_SHIFT, idxs,
                                       ws+WS_SAMPT, ws+WS_SAMP2T);
  head_apply_bf16<<<2048,256,0,stream>>>(xb, gq_w, ws+WS_GQ_SCALE, ws+WS_GQ_SHIFT, ws+WS_SEGG2);
  anchor2x_kernel<<<512,128,0,stream>>>(ws+WS_SEGX2, ws+WS_ANCHOR1, ws+WS_SEGG2, ws+WS_ANCHOR2);
  sim2_mfma<<<dim3(30,16),256,0,stream>>>(ws+WS_ANCHOR2, ws+WS_SAMP2T, ws+WS_SROW);
  lcon12_kernel<<<512,256,0,stream>>>(ws+WS_ANCHOR1, ws+WS_SAMPT, ws+WS_SROW, bg, out);
}

// Round 17
// 254.290 us; speedup vs baseline: 1.2425x; 1.2425x over previous
//
#include <hip/hip_runtime.h>
#include <math.h>

#define SK 7680          // 256 segments * 30 samples
#define NPTS 524288

// ---- workspace float offsets ----
#define WS_GQ_PART  0         // 32 partials x (96 sum + 96 sumsq)
#define WS_GK_PART  6144
#define WS_GQ_SCALE 12288
#define WS_GQ_SHIFT 12384
#define WS_GK_SCALE 12480
#define WS_GK_SHIFT 12576
#define WS_SEGX2    21888     // 256*96 raw view2 segment sums
#define WS_SEGG2    46464     // 256*96 head(view2) segment sums
#define WS_ANCHOR1  71040
#define WS_ANCHOR2  95616
#define WS_SAMPT    120192    // [7680][96] raw l2normed samples (row-major)
#define WS_SAMP2T   857472    // [7680][96] head l2normed samples (row-major)
#define WS_SROW     1594752   // [256][7680] sim2 matrix
#define WS_ZERO_CNT 71040     // zero partials + seg sums

typedef __attribute__((ext_vector_type(8))) short bf16x8;
typedef __attribute__((ext_vector_type(4))) float f32x4;

// 4x v_cvt_pk_bf16_f32 (RNE, HW)
__device__ __forceinline__ bf16x8 pack8(float4 a, float4 b){
  union { unsigned u[4]; bf16x8 v; } r;
  asm("v_cvt_pk_bf16_f32 %0, %1, %2" : "=v"(r.u[0]) : "v"(a.x), "v"(a.y));
  asm("v_cvt_pk_bf16_f32 %0, %1, %2" : "=v"(r.u[1]) : "v"(a.z), "v"(a.w));
  asm("v_cvt_pk_bf16_f32 %0, %1, %2" : "=v"(r.u[2]) : "v"(b.x), "v"(b.y));
  asm("v_cvt_pk_bf16_f32 %0, %1, %2" : "=v"(r.u[3]) : "v"(b.z), "v"(b.w));
  return r.v;
}
__device__ __forceinline__ float4 ld4(const float* p){
  return *reinterpret_cast<const float4*>(p);
}

// issue one 3-read group (no wait)
#define DS_ISSUE(r0,r1,r2,base,o0,o1,o2)                            \
  asm volatile("ds_read_b128 %0, %3 offset:" #o0 "\n\t"             \
               "ds_read_b128 %1, %3 offset:" #o1 "\n\t"             \
               "ds_read_b128 %2, %3 offset:" #o2                    \
               : "=v"(r0), "=v"(r1), "=v"(r2) : "v"(base));
// counted wait + scheduler fence (rule #18)
#define DS_WAIT(n)                                                  \
  asm volatile("s_waitcnt lgkmcnt(" #n ")" ::: "memory");           \
  __builtin_amdgcn_sched_barrier(0);

#define MFMA3(acc, wx0, wx1, wx2)                                   \
  acc=__builtin_amdgcn_mfma_f32_16x16x32_bf16(a0,wx0,acc,0,0,0);    \
  acc=__builtin_amdgcn_mfma_f32_16x16x32_bf16(a1,wx1,acc,0,0,0);    \
  acc=__builtin_amdgcn_mfma_f32_16x16x32_bf16(a2,wx2,acc,0,0,0);

// stage bf16 W fragments into LDS directly from fp32 W (waves 0-2, kt = wave id)
// frag (kt,ot): lane l holds W[ot*16+(l&15)][kt*32+(l>>4)*8 + j], j=0..7
__device__ __forceinline__ void stage_wfrag(const float* __restrict__ W, float* wlds, int w, int l){
  if (w < 3){
    const int g = l >> 4, lr = l & 15;
    #pragma unroll
    for (int ot=0; ot<6; ++ot){
      const float* wr = W + (ot*16+lr)*96 + w*32 + g*8;
      bf16x8 f = pack8(ld4(wr), ld4(wr+4));
      *reinterpret_cast<bf16x8*>(wlds + ((w*6+ot)*64 + l)*4) = f;
    }
  }
}

// ---- fused stats over BOTH views: per-channel sum/sumsq of y = x @ W^T
// (bias cancels in BN); v2 blocks also accumulate raw-x per-segment colsums.
// grid 4096: bid&1 ? v2 : v1, sub = bid>>1.
__global__ __launch_bounds__(256) void stats_both(
    const float* __restrict__ V1, const float* __restrict__ V2,
    const float* __restrict__ Wk, const float* __restrict__ Wq,
    float* __restrict__ gpartK, float* __restrict__ gpartQ,
    float* __restrict__ gseg)
{
  __shared__ __align__(16) float wlds[4608];     // 18432 B
  __shared__ float red[192];
  __shared__ float rsg[96];
  const int tid = threadIdx.x;
  const int l = tid & 63, w = tid >> 6;
  const int g = l >> 4, lr = l & 15;
  const int bid = blockIdx.x;
  const bool isv2 = (bid & 1);
  const int sub = bid >> 1;
  const float* X = isv2 ? V2 : V1;
  const float* W = isv2 ? Wq : Wk;

  stage_wfrag(W, wlds, w, l);
  if (tid < 192) red[tid]=0.f;
  if (isv2 && tid < 96) rsg[tid]=0.f;
  __syncthreads();

  const unsigned wbase = (unsigned)(uintptr_t)wlds + (unsigned)(l*16);

  float sY[6], sY2[6];
  #pragma unroll
  for (int ot=0; ot<6; ++ot){ sY[ot]=0.f; sY2[ot]=0.f; }
  float rs[24];
  #pragma unroll
  for (int t=0; t<24; ++t) rs[t]=0.f;

  const long base_row = (long)sub*256 + w*16 + lr;
  const float* xr0 = X + base_row*96 + g*8;

  float4 c0=ld4(xr0), c1=ld4(xr0+4), c2=ld4(xr0+32), c3=ld4(xr0+36), c4=ld4(xr0+64), c5=ld4(xr0+68);

#define STATS_OT(ot, wx0, wx1, wx2) {                               \
    f32x4 acc={0.f,0.f,0.f,0.f};                                    \
    MFMA3(acc, wx0, wx1, wx2)                                       \
    sY[ot]+=acc[0]+acc[1]+acc[2]+acc[3];                            \
    sY2[ot]=fmaf(acc[0],acc[0],fmaf(acc[1],acc[1],                  \
            fmaf(acc[2],acc[2],fmaf(acc[3],acc[3],sY2[ot])))); }

  #pragma unroll 1
  for (int it=0; it<4; ++it){
    float4 n0,n1,n2,n3,n4,n5;
    if (it<3){
      const float* xn = xr0 + (it+1)*6144;       // +64 rows
      n0=ld4(xn); n1=ld4(xn+4); n2=ld4(xn+32); n3=ld4(xn+36); n4=ld4(xn+64); n5=ld4(xn+68);
    }
    if (isv2){
      rs[0]+=c0.x; rs[1]+=c0.y; rs[2]+=c0.z; rs[3]+=c0.w;
      rs[4]+=c1.x; rs[5]+=c1.y; rs[6]+=c1.z; rs[7]+=c1.w;
      rs[8]+=c2.x; rs[9]+=c2.y; rs[10]+=c2.z; rs[11]+=c2.w;
      rs[12]+=c3.x; rs[13]+=c3.y; rs[14]+=c3.z; rs[15]+=c3.w;
      rs[16]+=c4.x; rs[17]+=c4.y; rs[18]+=c4.z; rs[19]+=c4.w;
      rs[20]+=c5.x; rs[21]+=c5.y; rs[22]+=c5.z; rs[23]+=c5.w;
    }
    bf16x8 a0 = pack8(c0,c1), a1 = pack8(c2,c3), a2 = pack8(c4,c5);
    bf16x8 wA0,wA1,wA2, wB0,wB1,wB2;
    DS_ISSUE(wA0,wA1,wA2, wbase, 0,6144,12288)
    DS_ISSUE(wB0,wB1,wB2, wbase, 1024,7168,13312)
    DS_WAIT(3) STATS_OT(0, wA0,wA1,wA2)
    DS_ISSUE(wA0,wA1,wA2, wbase, 2048,8192,14336)
    DS_WAIT(3) STATS_OT(1, wB0,wB1,wB2)
    DS_ISSUE(wB0,wB1,wB2, wbase, 3072,9216,15360)
    DS_WAIT(3) STATS_OT(2, wA0,wA1,wA2)
    DS_ISSUE(wA0,wA1,wA2, wbase, 4096,10240,16384)
    DS_WAIT(3) STATS_OT(3, wB0,wB1,wB2)
    DS_ISSUE(wB0,wB1,wB2, wbase, 5120,11264,17408)
    DS_WAIT(3) STATS_OT(4, wA0,wA1,wA2)
    DS_WAIT(0) STATS_OT(5, wB0,wB1,wB2)
    if (it<3){ c0=n0; c1=n1; c2=n2; c3=n3; c4=n4; c5=n5; }
  }
#undef STATS_OT

  #pragma unroll
  for (int ot=0; ot<6; ++ot){
    float s = sY[ot], s2 = sY2[ot];
    s  += __shfl_xor(s,16);  s  += __shfl_xor(s,32);
    s2 += __shfl_xor(s2,16); s2 += __shfl_xor(s2,32);
    if (g==0){
      atomicAdd(&red[ot*16+lr], s);
      atomicAdd(&red[96+ot*16+lr], s2);
    }
  }
  if (isv2){
    #pragma unroll
    for (int t=0; t<24; ++t){
      float s = rs[t];
      s += __shfl_xor(s,1); s += __shfl_xor(s,2);
      s += __shfl_xor(s,4); s += __shfl_xor(s,8);
      if (lr==0){
        int kt = t>>3, j = t&7;
        atomicAdd(&rsg[kt*32 + g*8 + j], s);
      }
    }
  }
  __syncthreads();
  if (tid<96){
    float* dst = (isv2 ? gpartQ : gpartK) + (sub & 31)*192;
    atomicAdd(dst+tid,    red[tid]);
    atomicAdd(dst+96+tid, red[96+tid]);
    if (isv2) atomicAdd(gseg + (sub>>3)*96 + tid, rsg[tid]);
  }
}

// ---- MFMA head pass 2 (view2): relu(BN(y)) per-segment per-channel sums
__global__ __launch_bounds__(256) void head_apply_mfma(
    const float* __restrict__ X, const float* __restrict__ W,
    const float* __restrict__ scale, const float* __restrict__ shift,
    float* __restrict__ gseg)
{
  __shared__ __align__(16) float wlds[4608];
  __shared__ float red[96];
  const int tid = threadIdx.x;
  const int l = tid & 63, w = tid >> 6;
  const int g = l >> 4, lr = l & 15;

  stage_wfrag(W, wlds, w, l);
  if (tid < 96) red[tid]=0.f;
  __syncthreads();

  const unsigned wbase = (unsigned)(uintptr_t)wlds + (unsigned)(l*16);

  float sc[6], sh[6], zs[6];
  #pragma unroll
  for (int ot=0; ot<6; ++ot){
    sc[ot]=scale[ot*16+lr]; sh[ot]=shift[ot*16+lr]; zs[ot]=0.f;
  }

  const long base_row = (long)blockIdx.x*256 + w*16 + lr;
  const float* xr0 = X + base_row*96 + g*8;

  float4 c0=ld4(xr0), c1=ld4(xr0+4), c2=ld4(xr0+32), c3=ld4(xr0+36), c4=ld4(xr0+64), c5=ld4(xr0+68);

#define ZS_OT(ot, wx0, wx1, wx2) {                                  \
    f32x4 acc={0.f,0.f,0.f,0.f};                                    \
    MFMA3(acc, wx0, wx1, wx2)                                       \
    zs[ot]+=fmaxf(fmaf(acc[0],sc[ot],sh[ot]),0.f)                   \
           +fmaxf(fmaf(acc[1],sc[ot],sh[ot]),0.f)                   \
           +fmaxf(fmaf(acc[2],sc[ot],sh[ot]),0.f)                   \
           +fmaxf(fmaf(acc[3],sc[ot],sh[ot]),0.f); }

  #pragma unroll 1
  for (int it=0; it<4; ++it){
    float4 n0,n1,n2,n3,n4,n5;
    if (it<3){
      const float* xn = xr0 + (it+1)*6144;
      n0=ld4(xn); n1=ld4(xn+4); n2=ld4(xn+32); n3=ld4(xn+36); n4=ld4(xn+64); n5=ld4(xn+68);
    }
    bf16x8 a0 = pack8(c0,c1), a1 = pack8(c2,c3), a2 = pack8(c4,c5);
    bf16x8 wA0,wA1,wA2, wB0,wB1,wB2;
    DS_ISSUE(wA0,wA1,wA2, wbase, 0,6144,12288)
    DS_ISSUE(wB0,wB1,wB2, wbase, 1024,7168,13312)
    DS_WAIT(3) ZS_OT(0, wA0,wA1,wA2)
    DS_ISSUE(wA0,wA1,wA2, wbase, 2048,8192,14336)
    DS_WAIT(3) ZS_OT(1, wB0,wB1,wB2)
    DS_ISSUE(wB0,wB1,wB2, wbase, 3072,9216,15360)
    DS_WAIT(3) ZS_OT(2, wA0,wA1,wA2)
    DS_ISSUE(wA0,wA1,wA2, wbase, 4096,10240,16384)
    DS_WAIT(3) ZS_OT(3, wB0,wB1,wB2)
    DS_ISSUE(wB0,wB1,wB2, wbase, 5120,11264,17408)
    DS_WAIT(3) ZS_OT(4, wA0,wA1,wA2)
    DS_WAIT(0) ZS_OT(5, wB0,wB1,wB2)
    if (it<3){ c0=n0; c1=n1; c2=n2; c3=n3; c4=n4; c5=n5; }
  }
#undef ZS_OT

  #pragma unroll
  for (int ot=0; ot<6; ++ot){
    float s = zs[ot];
    s += __shfl_xor(s,16); s += __shfl_xor(s,32);
    if (g==0) atomicAdd(&red[ot*16+lr], s);
  }
  __syncthreads();
  if (tid<96) atomicAdd(gseg + (blockIdx.x>>3)*96 + tid, red[tid]);
}

// BN scale/shift from 32 partial sums (training-mode batch stats, biased var)
__global__ void bn_params_kernel(const float* __restrict__ gq_gamma, const float* __restrict__ gq_beta,
                                 const float* __restrict__ gk_gamma, const float* __restrict__ gk_beta,
                                 float* __restrict__ ws)
{
  const int t = threadIdx.x;
  const float invN = 1.0f/(float)NPTS;
  if (t < 96){
    float s=0.f, s2=0.f;
    #pragma unroll 4
    for (int p=0;p<32;p++){
      s  += ws[WS_GQ_PART + p*192 + t];
      s2 += ws[WS_GQ_PART + p*192 + 96 + t];
    }
    float mu  = s*invN;
    float var = s2*invN - mu*mu;
    float sc  = gq_gamma[t]*rsqrtf(var + 1e-5f);
    ws[WS_GQ_SCALE+t] = sc;
    ws[WS_GQ_SHIFT+t] = gq_beta[t] - mu*sc;
  } else if (t < 192){
    int c = t-96;
    float s=0.f, s2=0.f;
    #pragma unroll 4
    for (int p=0;p<32;p++){
      s  += ws[WS_GK_PART + p*192 + c];
      s2 += ws[WS_GK_PART + p*192 + 96 + c];
    }
    float mu  = s*invN;
    float var = s2*invN - mu*mu;
    float sc  = gk_gamma[c]*rsqrtf(var + 1e-5f);
    ws[WS_GK_SCALE+c] = sc;
    ws[WS_GK_SHIFT+c] = gk_beta[c] - mu*sc;
  }
}

// both anchors in one launch
__global__ __launch_bounds__(128) void anchor2x_kernel(
    const float* __restrict__ seg1, float* __restrict__ dst1,
    const float* __restrict__ seg2, float* __restrict__ dst2)
{
  __shared__ float red[128];
  const int t = threadIdx.x, s = blockIdx.x & 255;
  const float* segsum = (blockIdx.x < 256) ? seg1 : seg2;
  float* dst          = (blockIdx.x < 256) ? dst1 : dst2;
  float m = 0.f;
  if (t<96) m = segsum[s*96+t] * (1.0f/2048.0f);
  red[t] = m*m;
  __syncthreads();
  for (int off=64; off>0; off>>=1){
    if (t<off) red[t]+=red[t+off];
    __syncthreads();
  }
  float inv = 1.0f/(sqrtf(red[0]) + 1e-7f);
  if (t<96) dst[s*96+t] = m*inv;
}

// ---- fp32 96x96 tile GEMM helpers (used only by samples_kernel) ----
__device__ __forceinline__ void fma_row(float4& acc, const float4 x,
    const float4 w0, const float4 w1, const float4 w2, const float4 w3){
  acc.x = fmaf(x.x,w0.x, fmaf(x.y,w1.x, fmaf(x.z,w2.x, fmaf(x.w,w3.x, acc.x))));
  acc.y = fmaf(x.x,w0.y, fmaf(x.y,w1.y, fmaf(x.z,w2.y, fmaf(x.w,w3.y, acc.y))));
  acc.z = fmaf(x.x,w0.z, fmaf(x.y,w1.z, fmaf(x.z,w2.z, fmaf(x.w,w3.z, acc.z))));
  acc.w = fmaf(x.x,w0.w, fmaf(x.y,w1.w, fmaf(x.z,w2.w, fmaf(x.w,w3.w, acc.w))));
}
__device__ __forceinline__ void load_W(const float* __restrict__ W, float* Ws, int tid){
  #pragma unroll
  for (int i=0;i<12;i++){
    int f = i*768 + tid*4;
    int oc = f/96, k = f%96;
    float4 w4 = *reinterpret_cast<const float4*>(W + f);
    Ws[(k+0)*100+oc]=w4.x; Ws[(k+1)*100+oc]=w4.y;
    Ws[(k+2)*100+oc]=w4.z; Ws[(k+3)*100+oc]=w4.w;
  }
}
__device__ __forceinline__ void gemm_tile(const float* Xs, const float* Ws,
    int ocg, int rowg, int r0, float4 acc[4]){
  const float4* Xs4 = reinterpret_cast<const float4*>(Xs);
  const float4* Ws4 = reinterpret_cast<const float4*>(Ws);
  acc[0]=acc[1]=acc[2]=acc[3]=make_float4(0.f,0.f,0.f,0.f);
  #pragma unroll 4
  for (int k4=0;k4<24;k4++){
    float4 w0 = Ws4[(k4*4+0)*25 + ocg];
    float4 w1 = Ws4[(k4*4+1)*25 + ocg];
    float4 w2 = Ws4[(k4*4+2)*25 + ocg];
    float4 w3 = Ws4[(k4*4+3)*25 + ocg];
    #pragma unroll
    for (int jj=0;jj<4;jj++){
      float4 xv = Xs4[(r0+jj)*25 + (k4 ^ rowg)];
      fma_row(acc[jj], xv, w0, w1, w2, w3);
    }
  }
}

// gather 32 sampled view1 rows -> raw l2norm + gk-head l2norm, stored ROW-MAJOR [7680][96]
__global__ __launch_bounds__(192) void samples_kernel(
    const float* __restrict__ V1, const float* __restrict__ W,
    const float* __restrict__ scale, const float* __restrict__ shift,
    const int* __restrict__ idxs,
    float* __restrict__ sampT, float* __restrict__ samp2T)
{
  __shared__ __align__(16) float Ws[9600];
  __shared__ __align__(16) float Xs[3200];
  __shared__ __align__(16) float Gs[3200];
  __shared__ float invr[32], invh[32];
  const int tid = threadIdx.x;
  const int ocg = tid % 24, rowg = tid / 24;
  const int oc0 = ocg*4,  r0  = rowg*4;
  load_W(W, Ws, tid);
  const int base = blockIdx.x * 32;
  #pragma unroll
  for (int i=0;i<4;i++){
    int f = i*768 + tid*4;
    int row = f/96, col = f%96;
    int g = idxs[base+row];
    float4 v = *reinterpret_cast<const float4*>(V1 + g*96 + col);
    *reinterpret_cast<float4*>(Xs + row*100 + (col ^ ((row>>2)<<2))) = v;
  }
  __syncthreads();
  if (tid<32){
    float s=0.f;
    #pragma unroll
    for (int k=0;k<96;k++){ float v=Xs[tid*100+(k^((tid>>2)<<2))]; s=fmaf(v,v,s); }
    invr[tid]=1.0f/(sqrtf(s)+1e-7f);
  }
  __syncthreads();
  {
    int rr=tid&31, kg=tid>>5;
    float inv=invr[rr];
    #pragma unroll
    for (int kk=0;kk<16;kk++){
      int k=kg*16+kk;
      sampT[(long)(base+rr)*96 + k] = Xs[rr*100 + (k ^ ((rr>>2)<<2))]*inv;
    }
  }
  float4 acc[4];
  gemm_tile(Xs, Ws, ocg, rowg, r0, acc);
  float4 sc = make_float4(scale[oc0],scale[oc0+1],scale[oc0+2],scale[oc0+3]);
  float4 sh = make_float4(shift[oc0],shift[oc0+1],shift[oc0+2],shift[oc0+3]);
  #pragma unroll
  for (int jj=0;jj<4;jj++){
    int rr=r0+jj;
    float4 g;
    g.x=fmaxf(fmaf(acc[jj].x,sc.x,sh.x),0.f);
    g.y=fmaxf(fmaf(acc[jj].y,sc.y,sh.y),0.f);
    g.z=fmaxf(fmaf(acc[jj].z,sc.z,sh.z),0.f);
    g.w=fmaxf(fmaf(acc[jj].w,sc.w,sh.w),0.f);
    *reinterpret_cast<float4*>(Gs + rr*100 + (oc0 ^ ((rr>>2)<<2))) = g;
  }
  __syncthreads();
  if (tid<32){
    float s=0.f;
    #pragma unroll
    for (int k=0;k<96;k++){ float v=Gs[tid*100+(k^((tid>>2)<<2))]; s=fmaf(v,v,s); }
    invh[tid]=1.0f/(sqrtf(s)+1e-7f);
  }
  __syncthreads();
  {
    int rr=tid&31, kg=tid>>5;
    float inv=invh[rr];
    #pragma unroll
    for (int kk=0;kk<16;kk++){
      int k=kg*16+kk;
      samp2T[(long)(base+rr)*96 + k] = Gs[rr*100 + (k ^ ((rr>>2)<<2))]*inv;
    }
  }
}

// ---- sim2 = anchor2 @ samples2^T via MFMA: grid (30 col-tiles, 16 row-tiles) ----
__global__ __launch_bounds__(256) void sim2_mfma(
    const float* __restrict__ anchor2, const float* __restrict__ samp2,  // samp2 [7680][96]
    float* __restrict__ srowG)
{
  const int tid = threadIdx.x;
  const int l = tid & 63, w = tid >> 6;
  const int g = l >> 4, lr = l & 15;
  const int rowbase = blockIdx.y * 16;
  const int colbase = blockIdx.x * 256 + w * 64;

  bf16x8 af[3];
  const float* ar = anchor2 + (rowbase + lr)*96 + g*8;
  #pragma unroll
  for (int kt=0; kt<3; ++kt)
    af[kt] = pack8(ld4(ar + kt*32), ld4(ar + kt*32 + 4));

  #pragma unroll
  for (int sub=0; sub<4; ++sub){
    const float* br = samp2 + (long)(colbase + sub*16 + lr)*96 + g*8;
    float4 b00 = ld4(br);    float4 b01 = ld4(br+4);
    float4 b10 = ld4(br+32); float4 b11 = ld4(br+36);
    float4 b20 = ld4(br+64); float4 b21 = ld4(br+68);
    f32x4 acc = {0.f,0.f,0.f,0.f};
    acc = __builtin_amdgcn_mfma_f32_16x16x32_bf16(af[0], pack8(b00,b01), acc, 0,0,0);
    acc = __builtin_amdgcn_mfma_f32_16x16x32_bf16(af[1], pack8(b10,b11), acc, 0,0,0);
    acc = __builtin_amdgcn_mfma_f32_16x16x32_bf16(af[2], pack8(b20,b21), acc, 0,0,0);
    const int col  = colbase + sub*16 + lr;
    const int row0 = rowbase + g*4;
    #pragma unroll
    for (int i=0;i<4;i++)
      srowG[(long)(row0+i)*SK + col] = acc[i];
  }
}

// ---- fused Lcon1 + Lcon2: blocks 0..255 lcon2, 256..511 lcon1 (wave 0 only)
__global__ __launch_bounds__(256) void lcon12_kernel(
    const float* __restrict__ anchor1, const float* __restrict__ sampT,
    const float* __restrict__ srowG, const int* __restrict__ bg,
    float* __restrict__ out)
{
  const int tid = threadIdx.x;
  if (blockIdx.x >= 256){
    __shared__ float a[96];
    const int r = blockIdx.x - 256;
    if (tid < 64){
      for (int i=tid;i<96;i+=64) a[i]=anchor1[r*96+i];
      int c = 0;
      if (tid<30) c = r*30+tid;
      else if (tid<60){
        int j = tid-30;
        int p = (int)((double)j * 7649.0 / 29.0);   // linspace(0, M-1, 30).astype(int32)
        c = (p < r*30) ? p : p+30;                  // skip own block
      }
      float s=0.f;
      if (tid<60){
        const float* sr = sampT + (long)c*96;
        #pragma unroll
        for (int k4=0;k4<24;k4++){
          float4 v = *reinterpret_cast<const float4*>(sr + k4*4);
          s = fmaf(a[k4*4+0],v.x, fmaf(a[k4*4+1],v.y,
              fmaf(a[k4*4+2],v.z, fmaf(a[k4*4+3],v.w, s))));
        }
      }
      float logit = 2.0f*s;                          // /T, T=0.5
      float se = (tid<60) ? expf(logit) : 0.f;
      float sp = (tid<30) ? logit : 0.f;
      #pragma unroll
      for (int off=32; off; off>>=1){ se += __shfl_xor(se,off); sp += __shfl_xor(sp,off); }
      if (tid==0){
        float row = sp*(1.0f/30.0f) - logf(se);
        atomicAdd(out, -row*(1.0f/256.0f));
      }
    }
    return;
  }
  __shared__ float wvv[4];
  __shared__ int   wcc[4];
  __shared__ int   winc_s;
  __shared__ int   sel[30];
  const int r = blockIdx.x;
  const int lane = tid & 63, wid = tid >> 6;
  const float* __restrict__ rowp = srowG + (long)r*SK;
  float val[30];
  #pragma unroll
  for (int j=0;j<30;j++) val[j] = rowp[(j<<8) + tid];
  unsigned mask=0; float possum=0.f;
  for (int it=0; it<30; ++it){
    float bv = -3.0e38f; int bc = 1<<30;
    #pragma unroll
    for (int j=0;j<30;j++){
      if (!((mask>>j)&1u)){
        float v = val[j]; int c = tid + (j<<8);
        if (v > bv || (v == bv && c < bc)){ bv=v; bc=c; }
      }
    }
    #pragma unroll
    for (int off=32; off; off>>=1){
      float ov = __shfl_xor(bv, off); int ocx = __shfl_xor(bc, off);
      if (ov > bv || (ov == bv && ocx < bc)){ bv=ov; bc=ocx; }
    }
    if (lane==0){ wvv[wid]=bv; wcc[wid]=bc; }
    __syncthreads();
    if (tid==0){
      float v=wvv[0]; int c=wcc[0];
      #pragma unroll
      for (int w2=1;w2<4;w2++){
        if (wvv[w2]>v || (wvv[w2]==v && wcc[w2]<c)){ v=wvv[w2]; c=wcc[w2]; }
      }
      winc_s=c; sel[it]=c; possum += v;
    }
    __syncthreads();
    int c = winc_s;
    if ((c & 255) == tid) mask |= 1u << (c >> 8);
  }
  const int bgr = bg[r];
  float se=0.f;
  #pragma unroll
  for (int j=0;j<30;j++){
    int c = tid + (j<<8);
    int seg = c/30;
    int bgc = bg[seg];
    bool nf = ((bgr!=0) ? (bgc==0) : (bgc!=0)) && (seg != r);
    if (nf) se += expf(2.0f*val[j]);
  }
  #pragma unroll
  for (int off=32; off; off>>=1) se += __shfl_xor(se, off);
  if (lane==0) wvv[wid]=se;
  __syncthreads();
  float ex=0.f;
  if (tid<30){
    int c = sel[tid]; int seg=c/30; int bgc=bg[seg];
    bool nf = ((bgr!=0) ? (bgc==0) : (bgc!=0)) && (seg != r);
    if (!nf) ex = expf(2.0f*rowp[c]);        // positive not already in denom via neg
  }
  if (wid==0){
    #pragma unroll
    for (int off=32; off; off>>=1) ex += __shfl_xor(ex, off);
  }
  if (tid==0){
    float lse = logf(wvv[0]+wvv[1]+wvv[2]+wvv[3] + ex);
    float row = possum*(2.0f/30.0f) - lse;
    atomicAdd(out, -row*(1.0f/256.0f));
  }
}

extern "C" void kernel_launch(void* const* d_in, const int* in_sizes, int n_in,
                              void* d_out, int out_size, void* d_ws, size_t ws_size,
                              hipStream_t stream) {
  (void)in_sizes; (void)n_in; (void)out_size; (void)ws_size;
  const float* v1       = (const float*)d_in[0];
  const float* v2       = (const float*)d_in[1];
  const float* gq_w     = (const float*)d_in[2];
  const float* gq_gamma = (const float*)d_in[4];
  const float* gq_beta  = (const float*)d_in[5];
  const float* gk_w     = (const float*)d_in[6];
  const float* gk_gamma = (const float*)d_in[8];
  const float* gk_beta  = (const float*)d_in[9];
  const int*   idxs     = (const int*)d_in[12];
  const int*   bg       = (const int*)d_in[13];
  float* ws  = (float*)d_ws;
  float* out = (float*)d_out;

  (void)hipMemsetAsync(ws, 0, (size_t)WS_ZERO_CNT*sizeof(float), stream);
  (void)hipMemsetAsync(out, 0, sizeof(float), stream);

  stats_both<<<4096,256,0,stream>>>(v1, v2, gk_w, gq_w,
                                    ws+WS_GK_PART, ws+WS_GQ_PART, ws+WS_SEGX2);
  bn_params_kernel<<<1,192,0,stream>>>(gq_gamma, gq_beta, gk_gamma, gk_beta, ws);
  samples_kernel<<<240,192,0,stream>>>(v1, gk_w, ws+WS_GK_SCALE, ws+WS_GK_SHIFT, idxs,
                                       ws+WS_SAMPT, ws+WS_SAMP2T);
  head_apply_mfma<<<2048,256,0,stream>>>(v2, gq_w, ws+WS_GQ_SCALE, ws+WS_GQ_SHIFT, ws+WS_SEGG2);
  anchor2x_kernel<<<512,128,0,stream>>>(ws+WS_SEGX2, ws+WS_ANCHOR1, ws+WS_SEGG2, ws+WS_ANCHOR2);
  sim2_mfma<<<dim3(30,16),256,0,stream>>>(ws+WS_ANCHOR2, ws+WS_SAMP2T, ws+WS_SROW);
  lcon12_kernel<<<512,256,0,stream>>>(ws+WS_ANCHOR1, ws+WS_SAMPT, ws+WS_SROW, bg, out);
}